// Round 15
// baseline (126.590 us; speedup 1.0000x reference)
//
#include <hip/hip_runtime.h>

typedef unsigned short u16;
typedef unsigned int u32;
typedef __attribute__((ext_vector_type(4))) float f32x4;
typedef __attribute__((ext_vector_type(8))) __bf16 bf16x8;
typedef __attribute__((ext_vector_type(2))) __bf16 bf16x2;

#define NEGINF (-1e30f)
#define QSCALE 0.18033688011112042f   // 0.125 * log2(e)

__device__ __forceinline__ u16 f32_to_bf16(float f) {
  union { float f; unsigned int u; } v;
  v.f = f;
  unsigned int u = v.u;
  u += 0x7fffu + ((u >> 16) & 1u);   // RNE
  return (u16)(u >> 16);
}

__device__ __forceinline__ u32 pk_bf16(float a, float b) {
  bf16x2 t;
  t.x = (__bf16)a;
  t.y = (__bf16)b;
  return __builtin_bit_cast(u32, t);
}

__device__ __forceinline__ f32x4 mfma_bf16(bf16x8 a, bf16x8 b, f32x4 c) {
  return __builtin_amdgcn_mfma_f32_16x16x32_bf16(a, b, c, 0, 0, 0);
}

// async global->LDS, 16B per lane, dest = uniform base + lane*16
#define GLOAD_LDS16(g, l) __builtin_amdgcn_global_load_lds( \
    (const __attribute__((address_space(1))) unsigned int*)(g), \
    (__attribute__((address_space(3))) unsigned int*)(l), 16, 0, 0)

// ---------------------------------------------------------------- converts (merged)
__global__ void k_cvt_all(const float4* __restrict__ x4, u16* __restrict__ xb,
                          const float* __restrict__ Wqkv, u16* __restrict__ wqkvb,
                          const float* __restrict__ Wproj, u16* __restrict__ wprojb) {
  const int bidx = (int)blockIdx.x;
  if (bidx < 12288) {
    int i = bidx * 256 + threadIdx.x;
    float4 v = x4[i];
    uint2 o;
    o.x = (unsigned int)f32_to_bf16(v.x) | ((unsigned int)f32_to_bf16(v.y) << 16);
    o.y = (unsigned int)f32_to_bf16(v.z) | ((unsigned int)f32_to_bf16(v.w) << 16);
    *(uint2*)(xb + (size_t)i * 4) = o;
  } else if (bidx < 14016) {
    int idx = (bidx - 12288) * 256 + threadIdx.x;
    if (idx < 384 * 1152) {
      int k = idx / 1152, n = idx - k * 1152;
      wqkvb[(size_t)n * 384 + k] = f32_to_bf16(Wqkv[idx]);
    }
  } else {
    int idx = (bidx - 14016) * 256 + threadIdx.x;
    if (idx < 384 * 384) {
      int k = idx / 384, n = idx - k * 384;
      wprojb[(size_t)n * 384 + k] = f32_to_bf16(Wproj[idx]);
    }
  }
}

// ---------------------------------------------------------------- QKV GEMM mainloop (NEW: 3-buf, 2-deep)
// BM=128, BN=64, BK=64, 4 waves (2x2). LDS 3x24KB = 72KB -> 2 blocks/CU.
// Prologue stages tiles 0,1; iter t: vmcnt(6) waits tile t (issued TWO
// compute phases ago), single raw barrier, sched_barrier stops the compiler
// hoisting STAGE above it, STAGE(t+2) into buf[(t+2)%3] (= buf[(t-1)%3],
// whose reads finished before barrier(t)), compute buf[t%3].
// SW=true: swapped operands -> acc = C^T (lane: col=m=l15, reg=4 consec n).
template <bool SW>
__device__ __forceinline__ void gemm128x64_p3(
    const u16* __restrict__ A, const u16* __restrict__ Bt,
    int mBase, int nBase, u16* lsA, u16* lsB,
    f32x4 acc[4][2], int lane, int wv, int wm, int wn) {
  const int tid = wv * 64 + lane;
  const int l15 = lane & 15;
  size_t aoff[4]; u32 aldso[4];
#pragma unroll
  for (int jj = 0; jj < 4; ++jj) {
    int c = jj * 256 + tid;               // A chunk id (16B), 1024/buffer
    int row = c >> 3;                     // 8 chunks per 64-elem row
    int kc = (c & 7) ^ (row & 7);         // inverse swizzle on source
    aoff[jj] = (size_t)(mBase + row) * 384 + kc * 8;
    aldso[jj] = (u32)c * 8;
  }
  size_t boff[2]; u32 bldso[2];
#pragma unroll
  for (int jj = 0; jj < 2; ++jj) {
    int c = jj * 256 + tid;               // B chunk id, 512/buffer
    int row = c >> 3;
    int kc = (c & 7) ^ (row & 7);
    boff[jj] = (size_t)(nBase + row) * 384 + kc * 8;
    bldso[jj] = (u32)c * 8;
  }

#define STAGE3(kt, buf) do { \
  _Pragma("unroll") \
  for (int jj = 0; jj < 4; ++jj) \
    GLOAD_LDS16(A + aoff[jj] + (kt), lsA + (buf) * 8192 + aldso[jj]); \
  _Pragma("unroll") \
  for (int jj = 0; jj < 2; ++jj) \
    GLOAD_LDS16(Bt + boff[jj] + (kt), lsB + (buf) * 4096 + bldso[jj]); \
  } while (0)

  STAGE3(0, 0);
  STAGE3(64, 1);
#pragma unroll
  for (int t = 0; t < 6; ++t) {
    if (t < 5) {
      asm volatile("s_waitcnt vmcnt(6)" ::: "memory");  // tile t landed; t+1 in flight
    } else {
      asm volatile("s_waitcnt vmcnt(0)" ::: "memory");
    }
    __builtin_amdgcn_s_barrier();
    __builtin_amdgcn_sched_barrier(0);   // keep STAGE below the barrier
    if (t < 4) STAGE3((t + 2) * 64, (t + 2) % 3);
    const char* bA = (const char*)(lsA + (t % 3) * 8192);
    const char* bB = (const char*)(lsB + (t % 3) * 4096);
#pragma unroll
    for (int ks = 0; ks < 2; ++ks) {
      bf16x8 af[4], bfr[2];
#pragma unroll
      for (int i = 0; i < 4; ++i) {
        int row = wm * 64 + i * 16 + l15;
        af[i] = *(const bf16x8*)(bA + row * 128 + (((ks * 4 + (lane >> 4)) ^ (row & 7)) << 4));
      }
#pragma unroll
      for (int j = 0; j < 2; ++j) {
        int row = wn * 32 + j * 16 + l15;
        bfr[j] = *(const bf16x8*)(bB + row * 128 + (((ks * 4 + (lane >> 4)) ^ (row & 7)) << 4));
      }
      __builtin_amdgcn_s_setprio(1);
#pragma unroll
      for (int i = 0; i < 4; ++i)
#pragma unroll
        for (int j = 0; j < 2; ++j)
          acc[i][j] = SW ? mfma_bf16(bfr[j], af[i], acc[i][j])
                         : mfma_bf16(af[i], bfr[j], acc[i][j]);
      __builtin_amdgcn_s_setprio(0);
    }
  }
#undef STAGE3
}

// ---------------------------------------------------------------- QKV GEMM
// Q pre-scaled by 0.125*log2(e) so attention uses raw exp2.
// Coalesced LDS-staged epilogue (R12-proven pattern, resized to 128x64/64x128).
__global__ __launch_bounds__(256, 2) void k_qkv(
    const u16* __restrict__ A, const u16* __restrict__ Bt,
    const float* __restrict__ bias,
    u16* __restrict__ Qb, u16* __restrict__ Kb, u16* __restrict__ Vtb) {
  __shared__ __align__(16) u16 lsA[3 * 8192];   // 48KB (epilogue reuses 16KB)
  __shared__ __align__(16) u16 lsB[3 * 4096];   // 24KB
  const int tid = threadIdx.x, lane = tid & 63, wv = tid >> 6;
  const int l15 = lane & 15, g = lane >> 4;
  const int wm = wv >> 1, wn = wv & 1;
  // XCD chunked swizzle: 4608 = 8 * 576
  const int bid = (int)blockIdx.x;
  const int wgid = (bid & 7) * 576 + (bid >> 3);
  const int mtile = wgid / 18, ntile = wgid % 18;
  const int mBase = mtile * 128, nBase = ntile * 64;
  const int part = ntile / 6;            // block-uniform: 0=q 1=k 2=v
  const int hh = ntile % 6;              // one head per N-tile
  const size_t bhh = (size_t)((mtile >> 1) * 6 + hh);
  const int tt0 = (mtile & 1) * 128;     // t-offset within the head
  char* ot = (char*)lsA;                 // 16KB output staging tile

  f32x4 acc[4][2] = {};
  if (part == 2) {
    // ---- V: normal C (lane: d=l15 fixed, reg r = 4 consec t) -> [64][128] tile
    gemm128x64_p3<false>(A, Bt, mBase, nBase, lsA, lsB, acc, lane, wv, wm, wn);
#pragma unroll
    for (int j = 0; j < 2; ++j) {
      int drow = wn * 32 + j * 16 + l15;
      float bv = bias[nBase + drow];
#pragma unroll
      for (int i = 0; i < 4; ++i) {
        int tl = wm * 64 + i * 16 + g * 4;   // local t, 0..127
        uint2 w;
        w.x = pk_bf16(acc[i][j][0] + bv, acc[i][j][1] + bv);
        w.y = pk_bf16(acc[i][j][2] + bv, acc[i][j][3] + bv);
        int byte = (drow * 256 + tl * 2) ^ ((drow & 7) << 4);
        *(uint2*)(ot + byte) = w;
      }
    }
    asm volatile("s_waitcnt lgkmcnt(0)" ::: "memory");
    __builtin_amdgcn_s_barrier();
#pragma unroll
    for (int p = 0; p < 4; ++p) {
      int idx = p * 256 + tid;
      int row = idx >> 4, c = idx & 15;      // 16 x 16B chunks per 256B row
      uint4 v = *(const uint4*)(ot + row * 256 + (((c ^ (row & 7)) << 4)));
      *(uint4*)(Vtb + (bhh * 64 + row) * 256 + tt0 + c * 8) = v;
    }
  } else {
    // ---- Q/K: C^T (lane: t=l15 fixed, reg r = 4 consec d) -> [128][64] tile
    gemm128x64_p3<true>(A, Bt, mBase, nBase, lsA, lsB, acc, lane, wv, wm, wn);
    const float scale = (part == 0) ? QSCALE : 1.0f;
    u16* dst = (part == 0) ? Qb : Kb;
#pragma unroll
    for (int j = 0; j < 2; ++j) {
      int dbase = wn * 32 + j * 16 + g * 4;
      float4 bv4 = *(const float4*)(bias + nBase + dbase);
#pragma unroll
      for (int i = 0; i < 4; ++i) {
        int trow = wm * 64 + i * 16 + l15;   // local t, 0..127
        uint2 w;
        w.x = pk_bf16((acc[i][j][0] + bv4.x) * scale, (acc[i][j][1] + bv4.y) * scale);
        w.y = pk_bf16((acc[i][j][2] + bv4.z) * scale, (acc[i][j][3] + bv4.w) * scale);
        int byte = (trow * 128 + dbase * 2) ^ ((trow & 7) << 4);
        *(uint2*)(ot + byte) = w;
      }
    }
    asm volatile("s_waitcnt lgkmcnt(0)" ::: "memory");
    __builtin_amdgcn_s_barrier();
#pragma unroll
    for (int p = 0; p < 4; ++p) {
      int idx = p * 256 + tid;
      int row = idx >> 3, c = idx & 7;       // 8 x 16B chunks per 128B row
      uint4 v = *(const uint4*)(ot + row * 128 + (((c ^ (row & 7)) << 4)));
      *(uint4*)(dst + (bhh * 256 + tt0 + row) * 64 + c * 8) = v;
    }
  }
}

// ---------------------------------------------------------------- attention (R14 champion)
// 4 strip-waves per 256-thr block, load-balanced {7,6,1,0}/{5,4,3,2};
// launch_bounds(256,3) -> VGPR cap ~170 (168 measured, no spill).
__global__ __launch_bounds__(256, 3) void k_attn(
    const u16* __restrict__ Qb, const u16* __restrict__ Kb,
    const u16* __restrict__ Vtb, u16* __restrict__ Ob) {
  __shared__ __align__(16) u16 lsP[4][32 * 64];   // per-wave 4KB slice
  const int lane = threadIdx.x & 63, wv = threadIdx.x >> 6;
  const int l15 = lane & 15, g = lane >> 4;
  const int s = blockIdx.y ? (5 - wv) : ((wv < 2) ? 7 - wv : 3 - wv);
  const int bh = blockIdx.x;
  const int b = bh / 6, h = bh % 6;
  const u16* Qh = Qb + (size_t)bh * (256 * 64);
  const u16* Kh = Kb + (size_t)bh * (256 * 64);
  const u16* Vh = Vtb + (size_t)bh * (64 * 256);
  const int ktiles = (s >> 1) + 1;             // causal 64-k tiles
  char* pbuf = (char*)&lsP[wv][0];

  bf16x8 qf[2][2];
#pragma unroll
  for (int ks = 0; ks < 2; ++ks)
#pragma unroll
    for (int iq = 0; iq < 2; ++iq)
      qf[ks][iq] = *(const bf16x8*)(Qh + (size_t)(s * 32 + iq * 16 + l15) * 64 + ks * 32 + g * 8);

  f32x4 o[4][2] = {};            // o[jd][iq] = O^T[d=jd*16+g*4+r][q=iq*16+l15]
  float rl[2] = {0.f, 0.f};

#pragma unroll 1
  for (int kt = 0; kt < ktiles; ++kt) {
    bf16x8 kf[2][4];
#pragma unroll
    for (int ks = 0; ks < 2; ++ks)
#pragma unroll
      for (int jk = 0; jk < 4; ++jk)
        kf[ks][jk] = *(const bf16x8*)(Kh + (size_t)(kt * 64 + jk * 16 + l15) * 64 + ks * 32 + g * 8);

    f32x4 st[4][2] = {};
    __builtin_amdgcn_s_setprio(1);
#pragma unroll
    for (int ks = 0; ks < 2; ++ks)
#pragma unroll
      for (int jk = 0; jk < 4; ++jk)
#pragma unroll
        for (int iq = 0; iq < 2; ++iq)
          st[jk][iq] = mfma_bf16(kf[ks][jk], qf[ks][iq], st[jk][iq]);
    __builtin_amdgcn_s_setprio(0);

    bf16x8 vf[2][4];
#pragma unroll
    for (int ks = 0; ks < 2; ++ks)
#pragma unroll
      for (int jd = 0; jd < 4; ++jd)
        vf[ks][jd] = *(const bf16x8*)(Vh + (size_t)(jd * 16 + l15) * 256 + kt * 64 + ks * 32 + g * 8);

    if (kt == ktiles - 1) {
#pragma unroll
      for (int jk = 0; jk < 4; ++jk)
#pragma unroll
        for (int iq = 0; iq < 2; ++iq)
#pragma unroll
          for (int r = 0; r < 4; ++r)
            if (kt * 64 + jk * 16 + g * 4 + r > s * 32 + iq * 16 + l15)
              st[jk][iq][r] = NEGINF;
    }

    float rs[2] = {0.f, 0.f};
#pragma unroll
    for (int jk = 0; jk < 4; ++jk)
#pragma unroll
      for (int iq = 0; iq < 2; ++iq) {
        float p0 = __builtin_amdgcn_exp2f(st[jk][iq][0]);
        float p1 = __builtin_amdgcn_exp2f(st[jk][iq][1]);
        float p2 = __builtin_amdgcn_exp2f(st[jk][iq][2]);
        float p3 = __builtin_amdgcn_exp2f(st[jk][iq][3]);
        rs[iq] += (p0 + p1) + (p2 + p3);
        int q = iq * 16 + l15;
        int byte = (q * 128 + (jk * 16 + g * 4) * 2) ^ ((q & 7) << 4);
        uint2 w;
        w.x = pk_bf16(p0, p1);
        w.y = pk_bf16(p2, p3);
        *(uint2*)(pbuf + byte) = w;
      }
#pragma unroll
    for (int iq = 0; iq < 2; ++iq) {
      float v = rs[iq];
      v += __shfl_xor(v, 16);
      v += __shfl_xor(v, 32);
      rl[iq] += v;
    }

#pragma unroll
    for (int ks = 0; ks < 2; ++ks) {
      bf16x8 pf[2];
#pragma unroll
      for (int iq = 0; iq < 2; ++iq) {
        int q = iq * 16 + l15;
        pf[iq] = *(const bf16x8*)(pbuf + ((q * 128 + ks * 64 + g * 16) ^ ((q & 7) << 4)));
      }
      __builtin_amdgcn_s_setprio(1);
#pragma unroll
      for (int jd = 0; jd < 4; ++jd)
#pragma unroll
        for (int iq = 0; iq < 2; ++iq)
          o[jd][iq] = mfma_bf16(vf[ks][jd], pf[iq], o[jd][iq]);
      __builtin_amdgcn_s_setprio(0);
    }
  }

  // Epilogue: normalize, transpose through LDS slice, coalesced 16B stores.
#pragma unroll
  for (int iq = 0; iq < 2; ++iq) {
    float inv = 1.0f / rl[iq];
    int q = iq * 16 + l15;
#pragma unroll
    for (int jd = 0; jd < 4; ++jd) {
      uint2 w;
      w.x = pk_bf16(o[jd][iq][0] * inv, o[jd][iq][1] * inv);
      w.y = pk_bf16(o[jd][iq][2] * inv, o[jd][iq][3] * inv);
      int byte = (q * 128 + jd * 32 + g * 8) ^ ((q & 7) << 4);
      *(uint2*)(pbuf + byte) = w;
    }
  }
  asm volatile("s_waitcnt lgkmcnt(0)" ::: "memory");
#pragma unroll
  for (int rep = 0; rep < 4; ++rep) {
    int row = rep * 8 + (lane >> 3);
    int c = lane & 7;
    uint4 v = *(const uint4*)(pbuf + row * 128 + ((c ^ (row & 7)) * 16));
    int t = s * 32 + row;
    *(uint4*)(Ob + ((size_t)(b * 256 + t)) * 384 + h * 64 + c * 8) = v;
  }
}

// ---------------------------------------------------------------- proj GEMM (R10-proven)
__device__ __forceinline__ void gemm128sq(
    const u16* __restrict__ A, const u16* __restrict__ Bt,
    int mBase, int nBase, u16* lsA, u16* lsB,
    f32x4 acc[4][4], int lane, int wv) {
  const int l15 = lane & 15, g = lane >> 4;
  const int wm = wv >> 1, wn = wv & 1;
  size_t aoff[4], boff[4];
  u32 ldso[4];
#pragma unroll
  for (int jj = 0; jj < 4; ++jj) {
    int c = jj * 256 + wv * 64 + lane;
    int row = c >> 3;
    int kc = (c & 7) ^ (row & 7);
    aoff[jj] = (size_t)(mBase + row) * 384 + kc * 8;
    boff[jj] = (size_t)(nBase + row) * 384 + kc * 8;
    ldso[jj] = (u32)c * 8;
  }
#pragma unroll 1
  for (int t = 0; t < 6; ++t) {
#pragma unroll
    for (int jj = 0; jj < 4; ++jj) {
      GLOAD_LDS16(A + aoff[jj] + t * 64, lsA + ldso[jj]);
      GLOAD_LDS16(Bt + boff[jj] + t * 64, lsB + ldso[jj]);
    }
    __syncthreads();
#pragma unroll
    for (int ks = 0; ks < 2; ++ks) {
      bf16x8 af[4], bfr[4];
#pragma unroll
      for (int i = 0; i < 4; ++i) {
        int row = wm * 64 + i * 16 + l15;
        af[i] = *(const bf16x8*)((const char*)lsA + row * 128 + (((ks * 4 + g) ^ (row & 7)) << 4));
      }
#pragma unroll
      for (int j = 0; j < 4; ++j) {
        int row = wn * 64 + j * 16 + l15;
        bfr[j] = *(const bf16x8*)((const char*)lsB + row * 128 + (((ks * 4 + g) ^ (row & 7)) << 4));
      }
      __builtin_amdgcn_s_setprio(1);
#pragma unroll
      for (int i = 0; i < 4; ++i)
#pragma unroll
        for (int j = 0; j < 4; ++j)
          acc[i][j] = mfma_bf16(af[i], bfr[j], acc[i][j]);
      __builtin_amdgcn_s_setprio(0);
    }
    __syncthreads();
  }
}

__global__ __launch_bounds__(256, 3) void k_proj(
    const u16* __restrict__ A, const u16* __restrict__ Bt,
    const float* __restrict__ bias, float* __restrict__ out) {
  __shared__ __align__(16) u16 lsA[8192];
  __shared__ __align__(16) u16 lsB[8192];
  const int tid = threadIdx.x, lane = tid & 63, wv = tid >> 6;
  const int l15 = lane & 15, g = lane >> 4;
  const int wm = wv >> 1, wn = wv & 1;
  // XCD chunked swizzle: 768 = 8 * 96
  const int bid = (int)blockIdx.x;
  const int wgid = (bid & 7) * 96 + (bid >> 3);
  const int mBase = (wgid / 3) * 128, nBase = (wgid % 3) * 128;
  f32x4 acc[4][4] = {};
  gemm128sq(A, Bt, mBase, nBase, lsA, lsB, acc, lane, wv);
#pragma unroll
  for (int j = 0; j < 4; ++j) {
    int col = nBase + wn * 64 + j * 16 + l15;
    float bv = bias[col];
#pragma unroll
    for (int i = 0; i < 4; ++i) {
      int m0 = mBase + wm * 64 + i * 16 + g * 4;
#pragma unroll
      for (int r = 0; r < 4; ++r)
        out[(size_t)(m0 + r) * 384 + col] = acc[i][j][r] + bv;
    }
  }
}

// ---------------------------------------------------------------- launch
extern "C" void kernel_launch(void* const* d_in, const int* in_sizes, int n_in,
                              void* d_out, int out_size, void* d_ws, size_t ws_size,
                              hipStream_t stream) {
  const float* x     = (const float*)d_in[0];   // [128,256,384]
  const float* Wqkv  = (const float*)d_in[1];   // [384,1152]
  const float* bqkv  = (const float*)d_in[2];   // [1152]
  const float* Wproj = (const float*)d_in[3];   // [384,384]
  const float* bproj = (const float*)d_in[4];   // [384]
  float* out = (float*)d_out;

  char* ws = (char*)d_ws;
  u16* xb     = (u16*)(ws);                       // 25,165,824 B
  u16* wqkvb  = (u16*)(ws + 25165824);            //    884,736 B
  u16* wprojb = (u16*)(ws + 26050560);            //    294,912 B
  u16* Qb     = (u16*)(ws + 26345472);            // [B,H,T,D]
  u16* Kb     = (u16*)(ws + 51511296);            // [B,H,T,D]
  u16* Vtb    = (u16*)(ws + 76677120);            // [B,H,D,T]
  u16* Ob     = (u16*)(ws + 101842944);           // [B,T,C]

  k_cvt_all<<<14592, 256, 0, stream>>>((const float4*)x, xb, Wqkv, wqkvb, Wproj, wprojb);
  k_qkv<<<4608, 256, 0, stream>>>(xb, wqkvb, bqkv, Qb, Kb, Vtb);
  k_attn<<<dim3(768, 2), 256, 0, stream>>>(Qb, Kb, Vtb, Ob);
  k_proj<<<768, 256, 0, stream>>>(Ob, wprojb, bproj, out);
}

// Round 16
// 116.572 us; speedup vs baseline: 1.0859x; 1.0859x over previous
//
#include <hip/hip_runtime.h>

typedef unsigned short u16;
typedef unsigned int u32;
typedef __attribute__((ext_vector_type(4))) float f32x4;
typedef __attribute__((ext_vector_type(8))) __bf16 bf16x8;
typedef __attribute__((ext_vector_type(2))) __bf16 bf16x2;

#define NEGINF (-1e30f)
#define QSCALE 0.18033688011112042f   // 0.125 * log2(e)

__device__ __forceinline__ u16 f32_to_bf16(float f) {
  union { float f; unsigned int u; } v;
  v.f = f;
  unsigned int u = v.u;
  u += 0x7fffu + ((u >> 16) & 1u);   // RNE
  return (u16)(u >> 16);
}

__device__ __forceinline__ u32 pk_bf16(float a, float b) {
  bf16x2 t;
  t.x = (__bf16)a;
  t.y = (__bf16)b;
  return __builtin_bit_cast(u32, t);
}

__device__ __forceinline__ f32x4 mfma_bf16(bf16x8 a, bf16x8 b, f32x4 c) {
  return __builtin_amdgcn_mfma_f32_16x16x32_bf16(a, b, c, 0, 0, 0);
}

// async global->LDS, 16B per lane, dest = uniform base + lane*16
#define GLOAD_LDS16(g, l) __builtin_amdgcn_global_load_lds( \
    (const __attribute__((address_space(1))) unsigned int*)(g), \
    (__attribute__((address_space(3))) unsigned int*)(l), 16, 0, 0)

// ---------------------------------------------------------------- converts (merged)
__global__ void k_cvt_all(const float4* __restrict__ x4, u16* __restrict__ xb,
                          const float* __restrict__ Wqkv, u16* __restrict__ wqkvb,
                          const float* __restrict__ Wproj, u16* __restrict__ wprojb) {
  const int bidx = (int)blockIdx.x;
  if (bidx < 12288) {
    int i = bidx * 256 + threadIdx.x;
    float4 v = x4[i];
    uint2 o;
    o.x = (unsigned int)f32_to_bf16(v.x) | ((unsigned int)f32_to_bf16(v.y) << 16);
    o.y = (unsigned int)f32_to_bf16(v.z) | ((unsigned int)f32_to_bf16(v.w) << 16);
    *(uint2*)(xb + (size_t)i * 4) = o;
  } else if (bidx < 14016) {
    int idx = (bidx - 12288) * 256 + threadIdx.x;
    if (idx < 384 * 1152) {
      int k = idx / 1152, n = idx - k * 1152;
      wqkvb[(size_t)n * 384 + k] = f32_to_bf16(Wqkv[idx]);
    }
  } else {
    int idx = (bidx - 14016) * 256 + threadIdx.x;
    if (idx < 384 * 384) {
      int k = idx / 384, n = idx - k * 384;
      wprojb[(size_t)n * 384 + k] = f32_to_bf16(Wproj[idx]);
    }
  }
}

// ---------------------------------------------------------------- GEMM mainloop (R12 champion — restored)
// BM=256, BN=64, BK=64, 8 waves (4x2). LDS 80KB -> 2 blocks/CU (16 waves).
// Double-buffered, counted vmcnt(5), raw barriers, XOR swizzle via source.
// SW=true: swapped operands -> acc = C^T (lane: col=t=l15, reg=4 consec d).
template <bool SW>
__device__ __forceinline__ void gemm256x64(
    const u16* __restrict__ A, const u16* __restrict__ Bt,
    int mBase, int nBase, u16* lsA, u16* lsB,
    f32x4 acc[4][2], int lane, int wv, int wm, int wn) {
  const int l15 = lane & 15;
  size_t aoff[4];
  u32 aldso[4];
#pragma unroll
  for (int jj = 0; jj < 4; ++jj) {
    int c = wv * 256 + jj * 64 + lane;    // A chunk id (16B), 2048/buffer
    int row = c >> 3;                     // 8 chunks per 64-elem row
    int kc = (c & 7) ^ (row & 7);         // inverse swizzle on source
    aoff[jj] = (size_t)(mBase + row) * 384 + kc * 8;
    aldso[jj] = (u32)(wv * 256 + jj * 64) * 8;
  }
  int cb = wv * 64 + lane;                // B chunk id, 512/buffer
  int brow = cb >> 3;
  size_t boff = (size_t)(nBase + brow) * 384 + (size_t)(((cb & 7) ^ (brow & 7)) * 8);
  u32 bldso = (u32)(wv * 64) * 8;

#define STAGE_T(kt, buf) do { \
  _Pragma("unroll") \
  for (int jj = 0; jj < 4; ++jj) \
    GLOAD_LDS16(A + aoff[jj] + (kt), lsA + (buf) * 16384 + aldso[jj]); \
  GLOAD_LDS16(Bt + boff + (kt), lsB + (buf) * 4096 + bldso); \
  } while (0)

  STAGE_T(0, 0);
#pragma unroll
  for (int t = 0; t < 6; ++t) {
    const int cur = t & 1;
    if (t < 5) {
      STAGE_T((t + 1) * 64, cur ^ 1);
      asm volatile("s_waitcnt vmcnt(5)" ::: "memory");  // tile t landed; t+1 in flight
    } else {
      asm volatile("s_waitcnt vmcnt(0)" ::: "memory");
    }
    __builtin_amdgcn_s_barrier();
    const char* bA = (const char*)(lsA + cur * 16384);
    const char* bB = (const char*)(lsB + cur * 4096);
#pragma unroll
    for (int ks = 0; ks < 2; ++ks) {
      bf16x8 af[4], bfr[2];
#pragma unroll
      for (int i = 0; i < 4; ++i) {
        int row = wm * 64 + i * 16 + l15;
        af[i] = *(const bf16x8*)(bA + row * 128 + (((ks * 4 + (lane >> 4)) ^ (row & 7)) << 4));
      }
#pragma unroll
      for (int j = 0; j < 2; ++j) {
        int row = wn * 32 + j * 16 + l15;
        bfr[j] = *(const bf16x8*)(bB + row * 128 + (((ks * 4 + (lane >> 4)) ^ (row & 7)) << 4));
      }
#pragma unroll
      for (int i = 0; i < 4; ++i)
#pragma unroll
        for (int j = 0; j < 2; ++j)
          acc[i][j] = SW ? mfma_bf16(bfr[j], af[i], acc[i][j])
                         : mfma_bf16(af[i], bfr[j], acc[i][j]);
    }
    __builtin_amdgcn_s_barrier();
  }
#undef STAGE_T
}

// ---------------------------------------------------------------- QKV GEMM (R12 champion — restored)
__global__ __launch_bounds__(512, 4) void k_qkv(
    const u16* __restrict__ A, const u16* __restrict__ Bt,
    const float* __restrict__ bias,
    u16* __restrict__ Qb, u16* __restrict__ Kb, u16* __restrict__ Vtb) {
  __shared__ __align__(16) u16 lsA[2 * 16384];   // 64KB (epilogue reuses 32KB)
  __shared__ __align__(16) u16 lsB[2 * 4096];    // 16KB
  const int tid = threadIdx.x, lane = tid & 63, wv = tid >> 6;
  const int l15 = lane & 15, g = lane >> 4;
  const int wm = wv >> 1, wn = wv & 1;
  // XCD chunked swizzle: 2304 = 8 * 288
  const int bid = (int)blockIdx.x;
  const int wgid = (bid & 7) * 288 + (bid >> 3);
  const int mtile = wgid / 18, ntile = wgid % 18;
  const int mBase = mtile * 256, nBase = ntile * 64;
  const int part = ntile / 6;            // block-uniform: 0=q 1=k 2=v
  const int hh = ntile % 6;              // one head per N-tile
  char* ot = (char*)lsA;                 // 32KB output staging tile

  f32x4 acc[4][2] = {};
  if (part == 2) {
    // ---- V: normal C (lane: d=l15 fixed, reg r = 4 consec t) -> [64][256] tile
    gemm256x64<false>(A, Bt, mBase, nBase, lsA, lsB, acc, lane, wv, wm, wn);
#pragma unroll
    for (int j = 0; j < 2; ++j) {
      int drow = wn * 32 + j * 16 + l15;
      float bv = bias[nBase + drow];
#pragma unroll
      for (int i = 0; i < 4; ++i) {
        int t0 = wm * 64 + i * 16 + g * 4;
        uint2 w;
        w.x = pk_bf16(acc[i][j][0] + bv, acc[i][j][1] + bv);
        w.y = pk_bf16(acc[i][j][2] + bv, acc[i][j][3] + bv);
        int byte = (drow * 512 + t0 * 2) ^ ((drow & 7) << 4);
        *(uint2*)(ot + byte) = w;
      }
    }
    asm volatile("s_waitcnt lgkmcnt(0)" ::: "memory");
    __builtin_amdgcn_s_barrier();
    size_t obase = (size_t)(mtile * 6 + hh) * (64 * 256);
#pragma unroll
    for (int p = 0; p < 4; ++p) {
      int idx = p * 512 + tid;
      int row = idx >> 5, c = idx & 31;      // 32 x 16B chunks per 512B row
      uint4 v = *(const uint4*)(ot + row * 512 + (((c ^ (row & 7)) << 4)));
      *(uint4*)(Vtb + obase + (size_t)row * 256 + c * 8) = v;
    }
  } else {
    // ---- Q/K: C^T (lane: t=l15 fixed, reg r = 4 consec d) -> [256][64] tile
    gemm256x64<true>(A, Bt, mBase, nBase, lsA, lsB, acc, lane, wv, wm, wn);
    const float scale = (part == 0) ? QSCALE : 1.0f;
    u16* dst = (part == 0) ? Qb : Kb;
#pragma unroll
    for (int j = 0; j < 2; ++j) {
      int dbase = wn * 32 + j * 16 + g * 4;
      float4 bv4 = *(const float4*)(bias + nBase + dbase);
#pragma unroll
      for (int i = 0; i < 4; ++i) {
        int trow = wm * 64 + i * 16 + l15;
        uint2 w;
        w.x = pk_bf16((acc[i][j][0] + bv4.x) * scale, (acc[i][j][1] + bv4.y) * scale);
        w.y = pk_bf16((acc[i][j][2] + bv4.z) * scale, (acc[i][j][3] + bv4.w) * scale);
        int byte = (trow * 128 + dbase * 2) ^ ((trow & 7) << 4);
        *(uint2*)(ot + byte) = w;
      }
    }
    asm volatile("s_waitcnt lgkmcnt(0)" ::: "memory");
    __builtin_amdgcn_s_barrier();
    size_t obase = (size_t)(mtile * 6 + hh) * (256 * 64);
#pragma unroll
    for (int p = 0; p < 4; ++p) {
      int idx = p * 512 + tid;
      int row = idx >> 3, c = idx & 7;       // 8 x 16B chunks per 128B row
      uint4 v = *(const uint4*)(ot + row * 128 + (((c ^ (row & 7)) << 4)));
      *(uint4*)(dst + obase + (size_t)row * 64 + c * 8) = v;
    }
  }
}

// ---------------------------------------------------------------- attention (R14 champion + XCD co-location)
// 4 strip-waves per 256-thr block, load-balanced {7,6,1,0}/{5,4,3,2};
// launch_bounds(256,3) -> VGPR cap ~170 (168 measured, no spill).
// NEW: 1-D grid 1536 = 8*192 with bijective chunked swizzle; id2 = bh*2+grp
// ordering puts both blocks of one (b,h) — which read the SAME K,V — in the
// same 192-block chunk -> same XCD -> K/V refetch becomes L2 hits (T1).
__global__ __launch_bounds__(256, 3) void k_attn(
    const u16* __restrict__ Qb, const u16* __restrict__ Kb,
    const u16* __restrict__ Vtb, u16* __restrict__ Ob) {
  __shared__ __align__(16) u16 lsP[4][32 * 64];   // per-wave 4KB slice
  const int lane = threadIdx.x & 63, wv = threadIdx.x >> 6;
  const int l15 = lane & 15, g = lane >> 4;
  const int bid = (int)blockIdx.x;
  const int id2 = (bid & 7) * 192 + (bid >> 3);   // bijective: 1536 = 8*192
  const int bh = id2 >> 1, grp = id2 & 1;
  const int s = grp ? (5 - wv) : ((wv < 2) ? 7 - wv : 3 - wv);
  const int b = bh / 6, h = bh % 6;
  const u16* Qh = Qb + (size_t)bh * (256 * 64);
  const u16* Kh = Kb + (size_t)bh * (256 * 64);
  const u16* Vh = Vtb + (size_t)bh * (64 * 256);
  const int ktiles = (s >> 1) + 1;             // causal 64-k tiles
  char* pbuf = (char*)&lsP[wv][0];

  bf16x8 qf[2][2];
#pragma unroll
  for (int ks = 0; ks < 2; ++ks)
#pragma unroll
    for (int iq = 0; iq < 2; ++iq)
      qf[ks][iq] = *(const bf16x8*)(Qh + (size_t)(s * 32 + iq * 16 + l15) * 64 + ks * 32 + g * 8);

  f32x4 o[4][2] = {};            // o[jd][iq] = O^T[d=jd*16+g*4+r][q=iq*16+l15]
  float rl[2] = {0.f, 0.f};

#pragma unroll 1
  for (int kt = 0; kt < ktiles; ++kt) {
    bf16x8 kf[2][4];
#pragma unroll
    for (int ks = 0; ks < 2; ++ks)
#pragma unroll
      for (int jk = 0; jk < 4; ++jk)
        kf[ks][jk] = *(const bf16x8*)(Kh + (size_t)(kt * 64 + jk * 16 + l15) * 64 + ks * 32 + g * 8);

    f32x4 st[4][2] = {};
    __builtin_amdgcn_s_setprio(1);
#pragma unroll
    for (int ks = 0; ks < 2; ++ks)
#pragma unroll
      for (int jk = 0; jk < 4; ++jk)
#pragma unroll
        for (int iq = 0; iq < 2; ++iq)
          st[jk][iq] = mfma_bf16(kf[ks][jk], qf[ks][iq], st[jk][iq]);
    __builtin_amdgcn_s_setprio(0);

    bf16x8 vf[2][4];
#pragma unroll
    for (int ks = 0; ks < 2; ++ks)
#pragma unroll
      for (int jd = 0; jd < 4; ++jd)
        vf[ks][jd] = *(const bf16x8*)(Vh + (size_t)(jd * 16 + l15) * 256 + kt * 64 + ks * 32 + g * 8);

    if (kt == ktiles - 1) {
#pragma unroll
      for (int jk = 0; jk < 4; ++jk)
#pragma unroll
        for (int iq = 0; iq < 2; ++iq)
#pragma unroll
          for (int r = 0; r < 4; ++r)
            if (kt * 64 + jk * 16 + g * 4 + r > s * 32 + iq * 16 + l15)
              st[jk][iq][r] = NEGINF;
    }

    float rs[2] = {0.f, 0.f};
#pragma unroll
    for (int jk = 0; jk < 4; ++jk)
#pragma unroll
      for (int iq = 0; iq < 2; ++iq) {
        float p0 = __builtin_amdgcn_exp2f(st[jk][iq][0]);
        float p1 = __builtin_amdgcn_exp2f(st[jk][iq][1]);
        float p2 = __builtin_amdgcn_exp2f(st[jk][iq][2]);
        float p3 = __builtin_amdgcn_exp2f(st[jk][iq][3]);
        rs[iq] += (p0 + p1) + (p2 + p3);
        int q = iq * 16 + l15;
        int byte = (q * 128 + (jk * 16 + g * 4) * 2) ^ ((q & 7) << 4);
        uint2 w;
        w.x = pk_bf16(p0, p1);
        w.y = pk_bf16(p2, p3);
        *(uint2*)(pbuf + byte) = w;
      }
#pragma unroll
    for (int iq = 0; iq < 2; ++iq) {
      float v = rs[iq];
      v += __shfl_xor(v, 16);
      v += __shfl_xor(v, 32);
      rl[iq] += v;
    }

#pragma unroll
    for (int ks = 0; ks < 2; ++ks) {
      bf16x8 pf[2];
#pragma unroll
      for (int iq = 0; iq < 2; ++iq) {
        int q = iq * 16 + l15;
        pf[iq] = *(const bf16x8*)(pbuf + ((q * 128 + ks * 64 + g * 16) ^ ((q & 7) << 4)));
      }
      __builtin_amdgcn_s_setprio(1);
#pragma unroll
      for (int jd = 0; jd < 4; ++jd)
#pragma unroll
        for (int iq = 0; iq < 2; ++iq)
          o[jd][iq] = mfma_bf16(vf[ks][jd], pf[iq], o[jd][iq]);
      __builtin_amdgcn_s_setprio(0);
    }
  }

  // Epilogue: normalize, transpose through LDS slice, coalesced 16B stores.
#pragma unroll
  for (int iq = 0; iq < 2; ++iq) {
    float inv = 1.0f / rl[iq];
    int q = iq * 16 + l15;
#pragma unroll
    for (int jd = 0; jd < 4; ++jd) {
      uint2 w;
      w.x = pk_bf16(o[jd][iq][0] * inv, o[jd][iq][1] * inv);
      w.y = pk_bf16(o[jd][iq][2] * inv, o[jd][iq][3] * inv);
      int byte = (q * 128 + jd * 32 + g * 8) ^ ((q & 7) << 4);
      *(uint2*)(pbuf + byte) = w;
    }
  }
  asm volatile("s_waitcnt lgkmcnt(0)" ::: "memory");
#pragma unroll
  for (int rep = 0; rep < 4; ++rep) {
    int row = rep * 8 + (lane >> 3);
    int c = lane & 7;
    uint4 v = *(const uint4*)(pbuf + row * 128 + ((c ^ (row & 7)) * 16));
    int t = s * 32 + row;
    *(uint4*)(Ob + ((size_t)(b * 256 + t)) * 384 + h * 64 + c * 8) = v;
  }
}

// ---------------------------------------------------------------- proj GEMM (R10-proven)
__device__ __forceinline__ void gemm128sq(
    const u16* __restrict__ A, const u16* __restrict__ Bt,
    int mBase, int nBase, u16* lsA, u16* lsB,
    f32x4 acc[4][4], int lane, int wv) {
  const int l15 = lane & 15, g = lane >> 4;
  const int wm = wv >> 1, wn = wv & 1;
  size_t aoff[4], boff[4];
  u32 ldso[4];
#pragma unroll
  for (int jj = 0; jj < 4; ++jj) {
    int c = jj * 256 + wv * 64 + lane;
    int row = c >> 3;
    int kc = (c & 7) ^ (row & 7);
    aoff[jj] = (size_t)(mBase + row) * 384 + kc * 8;
    boff[jj] = (size_t)(nBase + row) * 384 + kc * 8;
    ldso[jj] = (u32)c * 8;
  }
#pragma unroll 1
  for (int t = 0; t < 6; ++t) {
#pragma unroll
    for (int jj = 0; jj < 4; ++jj) {
      GLOAD_LDS16(A + aoff[jj] + t * 64, lsA + ldso[jj]);
      GLOAD_LDS16(Bt + boff[jj] + t * 64, lsB + ldso[jj]);
    }
    __syncthreads();
#pragma unroll
    for (int ks = 0; ks < 2; ++ks) {
      bf16x8 af[4], bfr[4];
#pragma unroll
      for (int i = 0; i < 4; ++i) {
        int row = wm * 64 + i * 16 + l15;
        af[i] = *(const bf16x8*)((const char*)lsA + row * 128 + (((ks * 4 + g) ^ (row & 7)) << 4));
      }
#pragma unroll
      for (int j = 0; j < 4; ++j) {
        int row = wn * 64 + j * 16 + l15;
        bfr[j] = *(const bf16x8*)((const char*)lsB + row * 128 + (((ks * 4 + g) ^ (row & 7)) << 4));
      }
      __builtin_amdgcn_s_setprio(1);
#pragma unroll
      for (int i = 0; i < 4; ++i)
#pragma unroll
        for (int j = 0; j < 4; ++j)
          acc[i][j] = mfma_bf16(af[i], bfr[j], acc[i][j]);
      __builtin_amdgcn_s_setprio(0);
    }
    __syncthreads();
  }
}

__global__ __launch_bounds__(256, 3) void k_proj(
    const u16* __restrict__ A, const u16* __restrict__ Bt,
    const float* __restrict__ bias, float* __restrict__ out) {
  __shared__ __align__(16) u16 lsA[8192];
  __shared__ __align__(16) u16 lsB[8192];
  const int tid = threadIdx.x, lane = tid & 63, wv = tid >> 6;
  const int l15 = lane & 15, g = lane >> 4;
  const int wm = wv >> 1, wn = wv & 1;
  // XCD chunked swizzle: 768 = 8 * 96
  const int bid = (int)blockIdx.x;
  const int wgid = (bid & 7) * 96 + (bid >> 3);
  const int mBase = (wgid / 3) * 128, nBase = (wgid % 3) * 128;
  f32x4 acc[4][4] = {};
  gemm128sq(A, Bt, mBase, nBase, lsA, lsB, acc, lane, wv);
#pragma unroll
  for (int j = 0; j < 4; ++j) {
    int col = nBase + wn * 64 + j * 16 + l15;
    float bv = bias[col];
#pragma unroll
    for (int i = 0; i < 4; ++i) {
      int m0 = mBase + wm * 64 + i * 16 + g * 4;
#pragma unroll
      for (int r = 0; r < 4; ++r)
        out[(size_t)(m0 + r) * 384 + col] = acc[i][j][r] + bv;
    }
  }
}

// ---------------------------------------------------------------- launch
extern "C" void kernel_launch(void* const* d_in, const int* in_sizes, int n_in,
                              void* d_out, int out_size, void* d_ws, size_t ws_size,
                              hipStream_t stream) {
  const float* x     = (const float*)d_in[0];   // [128,256,384]
  const float* Wqkv  = (const float*)d_in[1];   // [384,1152]
  const float* bqkv  = (const float*)d_in[2];   // [1152]
  const float* Wproj = (const float*)d_in[3];   // [384,384]
  const float* bproj = (const float*)d_in[4];   // [384]
  float* out = (float*)d_out;

  char* ws = (char*)d_ws;
  u16* xb     = (u16*)(ws);                       // 25,165,824 B
  u16* wqkvb  = (u16*)(ws + 25165824);            //    884,736 B
  u16* wprojb = (u16*)(ws + 26050560);            //    294,912 B
  u16* Qb     = (u16*)(ws + 26345472);            // [B,H,T,D]
  u16* Kb     = (u16*)(ws + 51511296);            // [B,H,T,D]
  u16* Vtb    = (u16*)(ws + 76677120);            // [B,H,D,T]
  u16* Ob     = (u16*)(ws + 101842944);           // [B,T,C]

  k_cvt_all<<<14592, 256, 0, stream>>>((const float4*)x, xb, Wqkv, wqkvb, Wproj, wprojb);
  k_qkv<<<2304, 512, 0, stream>>>(xb, wqkvb, bqkv, Qb, Kb, Vtb);
  k_attn<<<1536, 256, 0, stream>>>(Qb, Kb, Vtb, Ob);
  k_proj<<<768, 256, 0, stream>>>(Ob, wprojb, bproj, out);
}